// Round 4
// baseline (245.163 us; speedup 1.0000x reference)
//
#include <hip/hip_runtime.h>
#include <math.h>

#define S_LEN 2048
#define C_DIM 512
#define NH 16
#define HD 32
#define PLANE_U (NH * S_LEN * HD)   // 1,048,576 ushorts = 2MB per plane

typedef __attribute__((ext_vector_type(8))) short bf16x8;
typedef __attribute__((ext_vector_type(8))) unsigned short u16x8;
typedef __attribute__((ext_vector_type(4))) float f32x4;

__device__ __forceinline__ unsigned short f2b(float f) {
    unsigned int x = __float_as_uint(f);
    unsigned int r = (x + 0x7FFFu + ((x >> 16) & 1u)) >> 16;   // RNE
    return (unsigned short)r;
}

// split x into bf16 hi (truncated) + bf16 lo (RNE of residual): hi+lo ~ 2^-17 rel
__device__ __forceinline__ void cvt_hilo(float x, unsigned short& hi, unsigned short& lo) {
    unsigned int b = __float_as_uint(x);
    hi = (unsigned short)(b >> 16);
    float hif = __uint_as_float(b & 0xFFFF0000u);
    lo = f2b(x - hif);
}

// ---------------- projection: complex GEMM via bf16 MFMA, hi/lo split ------
// z<2 (q,k): D = W·X^T (rows=o, cols=s) -> store ushort4 along d in [h][s][d]
// z==2 (v):  D = X·W^T (rows=s, cols=o) -> store ushort4 along s in [h][d][s]
#define PROW 40   // padded LDS row stride in ushorts (80B, 16B-aligned)

__global__ __launch_bounds__(256)
void proj_mfma(const float* __restrict__ Q, const float* __restrict__ V,
               const float* __restrict__ K,
               const float* __restrict__ Wq, const float* __restrict__ bq,
               const float* __restrict__ Wk, const float* __restrict__ bk,
               const float* __restrict__ Wv, const float* __restrict__ bv,
               unsigned short* __restrict__ ws)
{
    const int z = blockIdx.z;
    const float *X, *W, *b;
    if (z == 0)      { X = Q; W = Wq; b = bq; }
    else if (z == 1) { X = K; W = Wk; b = bk; }
    else             { X = V; W = Wv; b = bv; }

    const int s0 = blockIdx.x * 64;
    const int o0 = blockIdx.y * 64;

    const float2 *Asrc, *Bsrc; int arow0, brow0;
    if (z < 2) { Asrc = (const float2*)W; arow0 = o0; Bsrc = (const float2*)X; brow0 = s0; }
    else       { Asrc = (const float2*)X; arow0 = s0; Bsrc = (const float2*)W; brow0 = o0; }

    __shared__ __align__(16) unsigned short LArh[64*PROW], LArl[64*PROW];
    __shared__ __align__(16) unsigned short LAih[64*PROW], LAil[64*PROW];
    __shared__ __align__(16) unsigned short LBrh[64*PROW], LBrl[64*PROW];
    __shared__ __align__(16) unsigned short LBih[64*PROW], LBil[64*PROW];

    const int t    = threadIdx.x;
    const int wave = t >> 6;
    const int lr   = t & 15;
    const int g    = (t & 63) >> 4;
    const int srow = t >> 2;        // staging row 0..63
    const int sk8  = (t & 3) * 8;   // staging k chunk (8 complex)

    const f32x4 zf = {0.f,0.f,0.f,0.f};
    f32x4 accR[4], accI[4];
    #pragma unroll
    for (int i = 0; i < 4; ++i) { accR[i] = zf; accI[i] = zf; }

    for (int k0 = 0; k0 < C_DIM; k0 += 32) {
        __syncthreads();
        // ---- stage A tile ----
        {
            const float4* s4 = (const float4*)(Asrc + (size_t)(arow0 + srow)*C_DIM + k0 + sk8);
            float4 f0 = s4[0], f1 = s4[1], f2v = s4[2], f3 = s4[3];
            float re[8] = {f0.x,f0.z,f1.x,f1.z,f2v.x,f2v.z,f3.x,f3.z};
            float im[8] = {f0.y,f0.w,f1.y,f1.w,f2v.y,f2v.w,f3.y,f3.w};
            u16x8 rh, rl, ih, il;
            #pragma unroll
            for (int j = 0; j < 8; ++j) {
                unsigned short h_, l_;
                cvt_hilo(re[j], h_, l_); rh[j] = h_; rl[j] = l_;
                cvt_hilo(im[j], h_, l_); ih[j] = h_; il[j] = l_;
            }
            int wb = srow*PROW + sk8;
            *(u16x8*)&LArh[wb] = rh; *(u16x8*)&LArl[wb] = rl;
            *(u16x8*)&LAih[wb] = ih; *(u16x8*)&LAil[wb] = il;
        }
        // ---- stage B tile ----
        {
            const float4* s4 = (const float4*)(Bsrc + (size_t)(brow0 + srow)*C_DIM + k0 + sk8);
            float4 f0 = s4[0], f1 = s4[1], f2v = s4[2], f3 = s4[3];
            float re[8] = {f0.x,f0.z,f1.x,f1.z,f2v.x,f2v.z,f3.x,f3.z};
            float im[8] = {f0.y,f0.w,f1.y,f1.w,f2v.y,f2v.w,f3.y,f3.w};
            u16x8 rh, rl, ih, il;
            #pragma unroll
            for (int j = 0; j < 8; ++j) {
                unsigned short h_, l_;
                cvt_hilo(re[j], h_, l_); rh[j] = h_; rl[j] = l_;
                cvt_hilo(im[j], h_, l_); ih[j] = h_; il[j] = l_;
            }
            int wb = srow*PROW + sk8;
            *(u16x8*)&LBrh[wb] = rh; *(u16x8*)&LBrl[wb] = rl;
            *(u16x8*)&LBih[wb] = ih; *(u16x8*)&LBil[wb] = il;
        }
        __syncthreads();

        // ---- A fragments (wave's 16 rows) ----
        const int ab = (wave*16 + lr)*PROW + g*8;
        bf16x8 aRH = *(const bf16x8*)&LArh[ab];
        bf16x8 aRL = *(const bf16x8*)&LArl[ab];
        bf16x8 aIH = *(const bf16x8*)&LAih[ab];
        bf16x8 aIL = *(const bf16x8*)&LAil[ab];
        bf16x8 aIHn, aILn;
        #pragma unroll
        for (int j = 0; j < 8; ++j) { aIHn[j] = aIH[j] ^ (short)0x8000; aILn[j] = aIL[j] ^ (short)0x8000; }

        #pragma unroll
        for (int tile = 0; tile < 4; ++tile) {
            const int bb = (tile*16 + lr)*PROW + g*8;
            bf16x8 bRH = *(const bf16x8*)&LBrh[bb];
            bf16x8 bRL = *(const bf16x8*)&LBrl[bb];
            bf16x8 bIH = *(const bf16x8*)&LBih[bb];
            bf16x8 bIL = *(const bf16x8*)&LBil[bb];
            // Re: aR*bR - aI*bI (hi*hi + hi*lo + lo*hi)
            accR[tile] = __builtin_amdgcn_mfma_f32_16x16x32_bf16(aRH,  bRH, accR[tile], 0,0,0);
            accR[tile] = __builtin_amdgcn_mfma_f32_16x16x32_bf16(aRL,  bRH, accR[tile], 0,0,0);
            accR[tile] = __builtin_amdgcn_mfma_f32_16x16x32_bf16(aRH,  bRL, accR[tile], 0,0,0);
            accR[tile] = __builtin_amdgcn_mfma_f32_16x16x32_bf16(aIHn, bIH, accR[tile], 0,0,0);
            accR[tile] = __builtin_amdgcn_mfma_f32_16x16x32_bf16(aILn, bIH, accR[tile], 0,0,0);
            accR[tile] = __builtin_amdgcn_mfma_f32_16x16x32_bf16(aIHn, bIL, accR[tile], 0,0,0);
            // Im: aR*bI + aI*bR
            accI[tile] = __builtin_amdgcn_mfma_f32_16x16x32_bf16(aRH,  bIH, accI[tile], 0,0,0);
            accI[tile] = __builtin_amdgcn_mfma_f32_16x16x32_bf16(aRL,  bIH, accI[tile], 0,0,0);
            accI[tile] = __builtin_amdgcn_mfma_f32_16x16x32_bf16(aRH,  bIL, accI[tile], 0,0,0);
            accI[tile] = __builtin_amdgcn_mfma_f32_16x16x32_bf16(aIH,  bRH, accI[tile], 0,0,0);
            accI[tile] = __builtin_amdgcn_mfma_f32_16x16x32_bf16(aIL,  bRH, accI[tile], 0,0,0);
            accI[tile] = __builtin_amdgcn_mfma_f32_16x16x32_bf16(aIH,  bRL, accI[tile], 0,0,0);
        }
    }

    // ---- epilogue ----
    const float2* b2 = (const float2*)b;
    if (z < 2) {
        unsigned short* pr = ws + (z == 0 ? 0 : 2) * (size_t)PLANE_U;
        unsigned short* pi = pr + PLANE_U;
        const int obase = o0 + wave*16 + g*4;
        const int h = obase >> 5, d0 = obase & 31;
        float bR[4], bI[4];
        #pragma unroll
        for (int r = 0; r < 4; ++r) { float2 bb = b2[obase + r]; bR[r] = bb.x; bI[r] = bb.y; }
        #pragma unroll
        for (int tile = 0; tile < 4; ++tile) {
            int s = s0 + tile*16 + lr;
            size_t idx = ((size_t)h*S_LEN + s)*HD + d0;
            ushort4 pkR, pkI;
            pkR.x = f2b(accR[tile][0]+bR[0]); pkR.y = f2b(accR[tile][1]+bR[1]);
            pkR.z = f2b(accR[tile][2]+bR[2]); pkR.w = f2b(accR[tile][3]+bR[3]);
            pkI.x = f2b(accI[tile][0]+bI[0]); pkI.y = f2b(accI[tile][1]+bI[1]);
            pkI.z = f2b(accI[tile][2]+bI[2]); pkI.w = f2b(accI[tile][3]+bI[3]);
            *(ushort4*)&pr[idx] = pkR;
            *(ushort4*)&pi[idx] = pkI;
        }
    } else {
        unsigned short* tr = ws + 4 * (size_t)PLANE_U;
        unsigned short* ti = tr + PLANE_U;
        const int sbase = s0 + wave*16 + g*4;
        #pragma unroll
        for (int tile = 0; tile < 4; ++tile) {
            int o = o0 + tile*16 + lr;
            int h = o >> 5, d = o & 31;
            float2 bb = b2[o];
            size_t idx = ((size_t)h*HD + d)*S_LEN + sbase;
            ushort4 pkR, pkI;
            pkR.x = f2b(accR[tile][0]+bb.x); pkR.y = f2b(accR[tile][1]+bb.x);
            pkR.z = f2b(accR[tile][2]+bb.x); pkR.w = f2b(accR[tile][3]+bb.x);
            pkI.x = f2b(accI[tile][0]+bb.y); pkI.y = f2b(accI[tile][1]+bb.y);
            pkI.z = f2b(accI[tile][2]+bb.y); pkI.w = f2b(accI[tile][3]+bb.y);
            *(ushort4*)&tr[idx] = pkR;
            *(ushort4*)&ti[idx] = pkI;
        }
    }
}

// ---------------- MFMA flash attention, block-cooperative split-K --------
// Block = 8 waves = ONE 16-row q-strip; wave w handles k in [w*256, w*256+256).
// No max tracking (|s| <= ~15, exp can't overflow; softmax shift-invariant)
// => partials (accO, l) are purely additive => LDS tree-sum at block end.
#define RED_F2 (8*16*32)          // 4096 float2 = 32KB partial-O region

__global__ __launch_bounds__(512, 8)
void attn_mfma(const unsigned short* __restrict__ ws, float* __restrict__ out)
{
    const int bid   = blockIdx.x;
    const int h     = bid & (NH - 1);   // bid%8 = head%8 -> per-XCD KV locality
    const int strip = bid >> 4;         // 0..127
    const int wave  = threadIdx.x >> 6; // 0..7 -> k-range owner
    const int lr    = threadIdx.x & 15;
    const int g     = (threadIdx.x & 63) >> 4;

    const unsigned short* qr  = ws + 0*(size_t)PLANE_U + (size_t)h*S_LEN*HD;
    const unsigned short* qi  = ws + 1*(size_t)PLANE_U + (size_t)h*S_LEN*HD;
    const unsigned short* kr  = ws + 2*(size_t)PLANE_U + (size_t)h*S_LEN*HD;
    const unsigned short* ki  = ws + 3*(size_t)PLANE_U + (size_t)h*S_LEN*HD;
    const unsigned short* vtr = ws + 4*(size_t)PLANE_U + (size_t)h*HD*S_LEN;
    const unsigned short* vti = ws + 5*(size_t)PLANE_U + (size_t)h*HD*S_LEN;

    const int q0 = strip * 16;

    bf16x8 aQr = *(const bf16x8*)&qr[(size_t)(q0 + lr)*HD + g*8];
    bf16x8 aQi = *(const bf16x8*)&qi[(size_t)(q0 + lr)*HD + g*8];
    bf16x8 aQrn;
    #pragma unroll
    for (int j = 0; j < 8; ++j) aQrn[j] = aQr[j] ^ (short)0x8000;

    // phase 1: per-wave 2KB P buffers (16KB); phase 2 (after barrier): the
    // same space is reused as the 32KB+512B partial-reduce region.
    __shared__ __align__(16) char smem[RED_F2*8 + 8*16*4];
    char* pb = smem + wave*2048;

    const f32x4 zf = {0.f, 0.f, 0.f, 0.f};
    f32x4 accO[2][2];
    #pragma unroll
    for (int dt = 0; dt < 2; ++dt) { accO[dt][0] = zf; accO[dt][1] = zf; }
    float l_run[4] = {0.f, 0.f, 0.f, 0.f};

    const int kbeg = wave * 256;
    for (int k0 = kbeg; k0 < kbeg + 256; k0 += 64) {
        // ---- QK^T: 4 tiles x 4 mfma (complex) ----
        f32x4 sR[4], sI[4];
        #pragma unroll
        for (int t = 0; t < 4; ++t) {
            const size_t krow = (size_t)(k0 + t*16 + lr)*HD + g*8;
            bf16x8 bKr = *(const bf16x8*)&kr[krow];
            bf16x8 bKi = *(const bf16x8*)&ki[krow];
            sR[t] = __builtin_amdgcn_mfma_f32_16x16x32_bf16(aQi,  bKi, zf,    0, 0, 0);
            sR[t] = __builtin_amdgcn_mfma_f32_16x16x32_bf16(aQr,  bKr, sR[t], 0, 0, 0);
            sI[t] = __builtin_amdgcn_mfma_f32_16x16x32_bf16(aQrn, bKi, zf,    0, 0, 0);
            sI[t] = __builtin_amdgcn_mfma_f32_16x16x32_bf16(aQi,  bKr, sI[t], 0, 0, 0);
        }
        // ---- p = exp(|s|/sqrt(32)) ----
        float p[4][4];
        const float sc2 = 1.0f / 32.0f;
        #pragma unroll
        for (int t = 0; t < 4; ++t)
            #pragma unroll
            for (int r = 0; r < 4; ++r)
                p[t][r] = __expf(__builtin_amdgcn_sqrtf(
                    fmaf(sR[t][r], sR[t][r], sI[t][r]*sI[t][r]) * sc2));
        #pragma unroll
        for (int r = 0; r < 4; ++r) {
            float rs = p[0][r] + p[1][r] + p[2][r] + p[3][r];
            rs += __shfl_xor(rs, 1);
            rs += __shfl_xor(rs, 2);
            rs += __shfl_xor(rs, 4);
            rs += __shfl_xor(rs, 8);
            l_run[r] += rs;
        }
        // ---- P -> LDS (bf16, swizzle byte ^= (row&7)<<4) ----
        #pragma unroll
        for (int t = 0; t < 4; ++t)
            #pragma unroll
            for (int r = 0; r < 4; ++r) {
                int row  = g*4 + r;
                int boff = (row*128 + (t*16 + lr)*2) ^ ((row & 7) << 4);
                *(unsigned short*)(pb + boff) = f2b(p[t][r]);
            }
        // ---- PV ----
        #pragma unroll
        for (int ks = 0; ks < 2; ++ks) {
            int rboff = (lr*128 + ks*64 + g*16) ^ ((lr & 7) << 4);
            bf16x8 aP = *(const bf16x8*)(pb + rboff);
            const size_t vcol = (size_t)k0 + ks*32 + g*8;
            #pragma unroll
            for (int dt = 0; dt < 2; ++dt) {
                bf16x8 bVr = *(const bf16x8*)&vtr[(size_t)(dt*16 + lr)*S_LEN + vcol];
                bf16x8 bVi = *(const bf16x8*)&vti[(size_t)(dt*16 + lr)*S_LEN + vcol];
                accO[dt][0] = __builtin_amdgcn_mfma_f32_16x16x32_bf16(aP, bVr, accO[dt][0], 0, 0, 0);
                accO[dt][1] = __builtin_amdgcn_mfma_f32_16x16x32_bf16(aP, bVi, accO[dt][1], 0, 0, 0);
            }
        }
    }

    // ---- block combine: all P buffers dead; alias smem as reduce region ----
    __syncthreads();
    float2* red  = (float2*)smem;                 // [8][16][32] complex partials
    float*  lred = (float*)(smem + RED_F2*8);     // [8][16]
    #pragma unroll
    for (int r = 0; r < 4; ++r) {
        int q = g*4 + r;
        #pragma unroll
        for (int dt = 0; dt < 2; ++dt) {
            int d = dt*16 + lr;
            red[wave*512 + q*32 + d] = make_float2(accO[dt][0][r], accO[dt][1][r]);
        }
        if (lr == 0) lred[wave*16 + q] = l_run[r];
    }
    __syncthreads();

    // thread i sums partials for output element (q = i>>5, d = i&31)
    {
        const int i = threadIdx.x;
        const int q = i >> 5, d = i & 31;
        float sr = 0.f, si = 0.f, sl = 0.f;
        #pragma unroll
        for (int w = 0; w < 8; ++w) {
            float2 v = red[w*512 + q*32 + d];
            sr += v.x; si += v.y;
            sl += lred[w*16 + q];
        }
        float inv = 1.0f / sl;
        float2* o2 = (float2*)out;
        o2[(size_t)(q0 + q)*C_DIM + h*HD + d] = make_float2(sr*inv, si*inv);
    }
}

extern "C" void kernel_launch(void* const* d_in, const int* in_sizes, int n_in,
                              void* d_out, int out_size, void* d_ws, size_t ws_size,
                              hipStream_t stream)
{
    const float* Q  = (const float*)d_in[0];
    const float* V  = (const float*)d_in[1];
    const float* K  = (const float*)d_in[2];
    const float* Wq = (const float*)d_in[3];
    const float* bq = (const float*)d_in[4];
    const float* Wk = (const float*)d_in[5];
    const float* bk = (const float*)d_in[6];
    const float* Wv = (const float*)d_in[7];
    const float* bv = (const float*)d_in[8];
    unsigned short* ws = (unsigned short*)d_ws;   // 6 planes * 2MB = 12MB
    float* out = (float*)d_out;

    dim3 gp(S_LEN/64, C_DIM/64, 3);
    proj_mfma<<<gp, 256, 0, stream>>>(Q, V, K, Wq, bq, Wk, bk, Wv, bv, ws);

    attn_mfma<<<dim3(128*NH), 512, 0, stream>>>(ws, out);
}

// Round 5
// 142.200 us; speedup vs baseline: 1.7241x; 1.7241x over previous
//
#include <hip/hip_runtime.h>
#include <math.h>

#define S_LEN 2048
#define C_DIM 512
#define NH 16
#define HD 32
#define PLANE_U (NH * S_LEN * HD)   // 1,048,576 ushorts = 2MB per plane

typedef __attribute__((ext_vector_type(8))) short bf16x8;
typedef __attribute__((ext_vector_type(8))) unsigned short u16x8;
typedef __attribute__((ext_vector_type(4))) float f32x4;

__device__ __forceinline__ unsigned short f2b(float f) {
    unsigned int x = __float_as_uint(f);
    unsigned int r = (x + 0x7FFFu + ((x >> 16) & 1u)) >> 16;   // RNE
    return (unsigned short)r;
}

// split x into bf16 hi (truncated) + bf16 lo (RNE of residual): hi+lo ~ 2^-17 rel
__device__ __forceinline__ void cvt_hilo(float x, unsigned short& hi, unsigned short& lo) {
    unsigned int b = __float_as_uint(x);
    hi = (unsigned short)(b >> 16);
    float hif = __uint_as_float(b & 0xFFFF0000u);
    lo = f2b(x - hif);
}

// ---------------- projection: complex GEMM via bf16 MFMA, hi/lo split ------
// z<2 (q,k): D = W·X^T (rows=o, cols=s) -> store ushort4 along d in [h][s][d]
// z==2 (v):  D = X·W^T (rows=s, cols=o) -> store ushort4 along s in [h][d][s]
#define PROW 40   // padded LDS row stride in ushorts (80B, 16B-aligned)

__global__ __launch_bounds__(256)
void proj_mfma(const float* __restrict__ Q, const float* __restrict__ V,
               const float* __restrict__ K,
               const float* __restrict__ Wq, const float* __restrict__ bq,
               const float* __restrict__ Wk, const float* __restrict__ bk,
               const float* __restrict__ Wv, const float* __restrict__ bv,
               unsigned short* __restrict__ ws)
{
    const int z = blockIdx.z;
    const float *X, *W, *b;
    if (z == 0)      { X = Q; W = Wq; b = bq; }
    else if (z == 1) { X = K; W = Wk; b = bk; }
    else             { X = V; W = Wv; b = bv; }

    const int s0 = blockIdx.x * 64;
    const int o0 = blockIdx.y * 64;

    const float2 *Asrc, *Bsrc; int arow0, brow0;
    if (z < 2) { Asrc = (const float2*)W; arow0 = o0; Bsrc = (const float2*)X; brow0 = s0; }
    else       { Asrc = (const float2*)X; arow0 = s0; Bsrc = (const float2*)W; brow0 = o0; }

    __shared__ __align__(16) unsigned short LArh[64*PROW], LArl[64*PROW];
    __shared__ __align__(16) unsigned short LAih[64*PROW], LAil[64*PROW];
    __shared__ __align__(16) unsigned short LBrh[64*PROW], LBrl[64*PROW];
    __shared__ __align__(16) unsigned short LBih[64*PROW], LBil[64*PROW];

    const int t    = threadIdx.x;
    const int wave = t >> 6;
    const int lr   = t & 15;
    const int g    = (t & 63) >> 4;
    const int srow = t >> 2;        // staging row 0..63
    const int sk8  = (t & 3) * 8;   // staging k chunk (8 complex)

    const f32x4 zf = {0.f,0.f,0.f,0.f};
    f32x4 accR[4], accI[4];
    #pragma unroll
    for (int i = 0; i < 4; ++i) { accR[i] = zf; accI[i] = zf; }

    for (int k0 = 0; k0 < C_DIM; k0 += 32) {
        __syncthreads();
        // ---- stage A tile ----
        {
            const float4* s4 = (const float4*)(Asrc + (size_t)(arow0 + srow)*C_DIM + k0 + sk8);
            float4 f0 = s4[0], f1 = s4[1], f2v = s4[2], f3 = s4[3];
            float re[8] = {f0.x,f0.z,f1.x,f1.z,f2v.x,f2v.z,f3.x,f3.z};
            float im[8] = {f0.y,f0.w,f1.y,f1.w,f2v.y,f2v.w,f3.y,f3.w};
            u16x8 rh, rl, ih, il;
            #pragma unroll
            for (int j = 0; j < 8; ++j) {
                unsigned short h_, l_;
                cvt_hilo(re[j], h_, l_); rh[j] = h_; rl[j] = l_;
                cvt_hilo(im[j], h_, l_); ih[j] = h_; il[j] = l_;
            }
            int wb = srow*PROW + sk8;
            *(u16x8*)&LArh[wb] = rh; *(u16x8*)&LArl[wb] = rl;
            *(u16x8*)&LAih[wb] = ih; *(u16x8*)&LAil[wb] = il;
        }
        // ---- stage B tile ----
        {
            const float4* s4 = (const float4*)(Bsrc + (size_t)(brow0 + srow)*C_DIM + k0 + sk8);
            float4 f0 = s4[0], f1 = s4[1], f2v = s4[2], f3 = s4[3];
            float re[8] = {f0.x,f0.z,f1.x,f1.z,f2v.x,f2v.z,f3.x,f3.z};
            float im[8] = {f0.y,f0.w,f1.y,f1.w,f2v.y,f2v.w,f3.y,f3.w};
            u16x8 rh, rl, ih, il;
            #pragma unroll
            for (int j = 0; j < 8; ++j) {
                unsigned short h_, l_;
                cvt_hilo(re[j], h_, l_); rh[j] = h_; rl[j] = l_;
                cvt_hilo(im[j], h_, l_); ih[j] = h_; il[j] = l_;
            }
            int wb = srow*PROW + sk8;
            *(u16x8*)&LBrh[wb] = rh; *(u16x8*)&LBrl[wb] = rl;
            *(u16x8*)&LBih[wb] = ih; *(u16x8*)&LBil[wb] = il;
        }
        __syncthreads();

        // ---- A fragments (wave's 16 rows) ----
        const int ab = (wave*16 + lr)*PROW + g*8;
        bf16x8 aRH = *(const bf16x8*)&LArh[ab];
        bf16x8 aRL = *(const bf16x8*)&LArl[ab];
        bf16x8 aIH = *(const bf16x8*)&LAih[ab];
        bf16x8 aIL = *(const bf16x8*)&LAil[ab];
        bf16x8 aIHn, aILn;
        #pragma unroll
        for (int j = 0; j < 8; ++j) { aIHn[j] = aIH[j] ^ (short)0x8000; aILn[j] = aIL[j] ^ (short)0x8000; }

        #pragma unroll
        for (int tile = 0; tile < 4; ++tile) {
            const int bb = (tile*16 + lr)*PROW + g*8;
            bf16x8 bRH = *(const bf16x8*)&LBrh[bb];
            bf16x8 bRL = *(const bf16x8*)&LBrl[bb];
            bf16x8 bIH = *(const bf16x8*)&LBih[bb];
            bf16x8 bIL = *(const bf16x8*)&LBil[bb];
            // Re: aR*bR - aI*bI (hi*hi + hi*lo + lo*hi)
            accR[tile] = __builtin_amdgcn_mfma_f32_16x16x32_bf16(aRH,  bRH, accR[tile], 0,0,0);
            accR[tile] = __builtin_amdgcn_mfma_f32_16x16x32_bf16(aRL,  bRH, accR[tile], 0,0,0);
            accR[tile] = __builtin_amdgcn_mfma_f32_16x16x32_bf16(aRH,  bRL, accR[tile], 0,0,0);
            accR[tile] = __builtin_amdgcn_mfma_f32_16x16x32_bf16(aIHn, bIH, accR[tile], 0,0,0);
            accR[tile] = __builtin_amdgcn_mfma_f32_16x16x32_bf16(aILn, bIH, accR[tile], 0,0,0);
            accR[tile] = __builtin_amdgcn_mfma_f32_16x16x32_bf16(aIHn, bIL, accR[tile], 0,0,0);
            // Im: aR*bI + aI*bR
            accI[tile] = __builtin_amdgcn_mfma_f32_16x16x32_bf16(aRH,  bIH, accI[tile], 0,0,0);
            accI[tile] = __builtin_amdgcn_mfma_f32_16x16x32_bf16(aRL,  bIH, accI[tile], 0,0,0);
            accI[tile] = __builtin_amdgcn_mfma_f32_16x16x32_bf16(aRH,  bIL, accI[tile], 0,0,0);
            accI[tile] = __builtin_amdgcn_mfma_f32_16x16x32_bf16(aIH,  bRH, accI[tile], 0,0,0);
            accI[tile] = __builtin_amdgcn_mfma_f32_16x16x32_bf16(aIL,  bRH, accI[tile], 0,0,0);
            accI[tile] = __builtin_amdgcn_mfma_f32_16x16x32_bf16(aIH,  bRL, accI[tile], 0,0,0);
        }
    }

    // ---- epilogue ----
    const float2* b2 = (const float2*)b;
    if (z < 2) {
        unsigned short* pr = ws + (z == 0 ? 0 : 2) * (size_t)PLANE_U;
        unsigned short* pi = pr + PLANE_U;
        const int obase = o0 + wave*16 + g*4;
        const int h = obase >> 5, d0 = obase & 31;
        float bR[4], bI[4];
        #pragma unroll
        for (int r = 0; r < 4; ++r) { float2 bb = b2[obase + r]; bR[r] = bb.x; bI[r] = bb.y; }
        #pragma unroll
        for (int tile = 0; tile < 4; ++tile) {
            int s = s0 + tile*16 + lr;
            size_t idx = ((size_t)h*S_LEN + s)*HD + d0;
            ushort4 pkR, pkI;
            pkR.x = f2b(accR[tile][0]+bR[0]); pkR.y = f2b(accR[tile][1]+bR[1]);
            pkR.z = f2b(accR[tile][2]+bR[2]); pkR.w = f2b(accR[tile][3]+bR[3]);
            pkI.x = f2b(accI[tile][0]+bI[0]); pkI.y = f2b(accI[tile][1]+bI[1]);
            pkI.z = f2b(accI[tile][2]+bI[2]); pkI.w = f2b(accI[tile][3]+bI[3]);
            *(ushort4*)&pr[idx] = pkR;
            *(ushort4*)&pi[idx] = pkI;
        }
    } else {
        unsigned short* tr = ws + 4 * (size_t)PLANE_U;
        unsigned short* ti = tr + PLANE_U;
        const int sbase = s0 + wave*16 + g*4;
        #pragma unroll
        for (int tile = 0; tile < 4; ++tile) {
            int o = o0 + tile*16 + lr;
            int h = o >> 5, d = o & 31;
            float2 bb = b2[o];
            size_t idx = ((size_t)h*HD + d)*S_LEN + sbase;
            ushort4 pkR, pkI;
            pkR.x = f2b(accR[tile][0]+bb.x); pkR.y = f2b(accR[tile][1]+bb.x);
            pkR.z = f2b(accR[tile][2]+bb.x); pkR.w = f2b(accR[tile][3]+bb.x);
            pkI.x = f2b(accI[tile][0]+bb.y); pkI.y = f2b(accI[tile][1]+bb.y);
            pkI.z = f2b(accI[tile][2]+bb.y); pkI.w = f2b(accI[tile][3]+bb.y);
            *(ushort4*)&tr[idx] = pkR;
            *(ushort4*)&ti[idx] = pkI;
        }
    }
}

// ---------------- MFMA flash attention, block-cooperative split-K --------
// Block = 8 waves = ONE 16-row q-strip; wave w handles k in [w*256, w*256+256).
// No max tracking (|s| <= ~15, exp can't overflow; softmax shift-invariant)
// => partials (accO, l) are purely additive => LDS tree-sum at block end.
// NOTE: launch_bounds min-waves MUST stay at 4 (128 VGPR budget) — 8 forces
// a 32-VGPR cap and spills accumulators to scratch (round-4: 487MB HBM writes).
#define RED_F2 (8*16*32)          // 4096 float2 = 32KB partial-O region

__global__ __launch_bounds__(512, 4)
void attn_mfma(const unsigned short* __restrict__ ws, float* __restrict__ out)
{
    const int bid   = blockIdx.x;
    const int h     = bid & (NH - 1);   // bid%8 = head%8 -> per-XCD KV locality
    const int strip = bid >> 4;         // 0..127
    const int wave  = threadIdx.x >> 6; // 0..7 -> k-range owner
    const int lr    = threadIdx.x & 15;
    const int g     = (threadIdx.x & 63) >> 4;

    const unsigned short* qr  = ws + 0*(size_t)PLANE_U + (size_t)h*S_LEN*HD;
    const unsigned short* qi  = ws + 1*(size_t)PLANE_U + (size_t)h*S_LEN*HD;
    const unsigned short* kr  = ws + 2*(size_t)PLANE_U + (size_t)h*S_LEN*HD;
    const unsigned short* ki  = ws + 3*(size_t)PLANE_U + (size_t)h*S_LEN*HD;
    const unsigned short* vtr = ws + 4*(size_t)PLANE_U + (size_t)h*HD*S_LEN;
    const unsigned short* vti = ws + 5*(size_t)PLANE_U + (size_t)h*HD*S_LEN;

    const int q0 = strip * 16;

    bf16x8 aQr = *(const bf16x8*)&qr[(size_t)(q0 + lr)*HD + g*8];
    bf16x8 aQi = *(const bf16x8*)&qi[(size_t)(q0 + lr)*HD + g*8];
    bf16x8 aQrn;
    #pragma unroll
    for (int j = 0; j < 8; ++j) aQrn[j] = aQr[j] ^ (short)0x8000;

    // phase 1: per-wave 2KB P buffers (16KB); phase 2 (after barrier): the
    // same space is reused as the 32KB+512B partial-reduce region.
    __shared__ __align__(16) char smem[RED_F2*8 + 8*16*4];
    char* pb = smem + wave*2048;

    const f32x4 zf = {0.f, 0.f, 0.f, 0.f};
    f32x4 accO[2][2];
    #pragma unroll
    for (int dt = 0; dt < 2; ++dt) { accO[dt][0] = zf; accO[dt][1] = zf; }
    float l_lane[4] = {0.f, 0.f, 0.f, 0.f};   // per-lane partial; shfl once at end

    const int kbeg = wave * 256;
    for (int k0 = kbeg; k0 < kbeg + 256; k0 += 64) {
        // ---- QK^T: 4 tiles x 4 mfma (complex) ----
        f32x4 sR[4], sI[4];
        #pragma unroll
        for (int t = 0; t < 4; ++t) {
            const size_t krow = (size_t)(k0 + t*16 + lr)*HD + g*8;
            bf16x8 bKr = *(const bf16x8*)&kr[krow];
            bf16x8 bKi = *(const bf16x8*)&ki[krow];
            sR[t] = __builtin_amdgcn_mfma_f32_16x16x32_bf16(aQi,  bKi, zf,    0, 0, 0);
            sR[t] = __builtin_amdgcn_mfma_f32_16x16x32_bf16(aQr,  bKr, sR[t], 0, 0, 0);
            sI[t] = __builtin_amdgcn_mfma_f32_16x16x32_bf16(aQrn, bKi, zf,    0, 0, 0);
            sI[t] = __builtin_amdgcn_mfma_f32_16x16x32_bf16(aQi,  bKr, sI[t], 0, 0, 0);
        }
        // ---- p = exp(|s|/sqrt(32)) ----
        float p[4][4];
        const float sc2 = 1.0f / 32.0f;
        #pragma unroll
        for (int t = 0; t < 4; ++t)
            #pragma unroll
            for (int r = 0; r < 4; ++r)
                p[t][r] = __expf(__builtin_amdgcn_sqrtf(
                    fmaf(sR[t][r], sR[t][r], sI[t][r]*sI[t][r]) * sc2));
        #pragma unroll
        for (int r = 0; r < 4; ++r)
            l_lane[r] += p[0][r] + p[1][r] + p[2][r] + p[3][r];
        // ---- P -> LDS (bf16, swizzle byte ^= (row&7)<<4) ----
        #pragma unroll
        for (int t = 0; t < 4; ++t)
            #pragma unroll
            for (int r = 0; r < 4; ++r) {
                int row  = g*4 + r;
                int boff = (row*128 + (t*16 + lr)*2) ^ ((row & 7) << 4);
                *(unsigned short*)(pb + boff) = f2b(p[t][r]);
            }
        // ---- PV ----
        #pragma unroll
        for (int ks = 0; ks < 2; ++ks) {
            int rboff = (lr*128 + ks*64 + g*16) ^ ((lr & 7) << 4);
            bf16x8 aP = *(const bf16x8*)(pb + rboff);
            const size_t vcol = (size_t)k0 + ks*32 + g*8;
            #pragma unroll
            for (int dt = 0; dt < 2; ++dt) {
                bf16x8 bVr = *(const bf16x8*)&vtr[(size_t)(dt*16 + lr)*S_LEN + vcol];
                bf16x8 bVi = *(const bf16x8*)&vti[(size_t)(dt*16 + lr)*S_LEN + vcol];
                accO[dt][0] = __builtin_amdgcn_mfma_f32_16x16x32_bf16(aP, bVr, accO[dt][0], 0, 0, 0);
                accO[dt][1] = __builtin_amdgcn_mfma_f32_16x16x32_bf16(aP, bVi, accO[dt][1], 0, 0, 0);
            }
        }
    }

    // ---- wave l-reduction (once, outside the k-loop) ----
    float l_run[4];
    #pragma unroll
    for (int r = 0; r < 4; ++r) {
        float rs = l_lane[r];
        rs += __shfl_xor(rs, 1);
        rs += __shfl_xor(rs, 2);
        rs += __shfl_xor(rs, 4);
        rs += __shfl_xor(rs, 8);
        l_run[r] = rs;
    }

    // ---- block combine: all P buffers dead; alias smem as reduce region ----
    __syncthreads();
    float2* red  = (float2*)smem;                 // [8][16][32] complex partials
    float*  lred = (float*)(smem + RED_F2*8);     // [8][16]
    #pragma unroll
    for (int r = 0; r < 4; ++r) {
        int q = g*4 + r;
        #pragma unroll
        for (int dt = 0; dt < 2; ++dt) {
            int d = dt*16 + lr;
            red[wave*512 + q*32 + d] = make_float2(accO[dt][0][r], accO[dt][1][r]);
        }
        if (lr == 0) lred[wave*16 + q] = l_run[r];
    }
    __syncthreads();

    // thread i sums partials for output element (q = i>>5, d = i&31)
    {
        const int i = threadIdx.x;
        const int q = i >> 5, d = i & 31;
        float sr = 0.f, si = 0.f, sl = 0.f;
        #pragma unroll
        for (int w = 0; w < 8; ++w) {
            float2 v = red[w*512 + q*32 + d];
            sr += v.x; si += v.y;
            sl += lred[w*16 + q];
        }
        float inv = 1.0f / sl;
        float2* o2 = (float2*)out;
        o2[(size_t)(q0 + q)*C_DIM + h*HD + d] = make_float2(sr*inv, si*inv);
    }
}

extern "C" void kernel_launch(void* const* d_in, const int* in_sizes, int n_in,
                              void* d_out, int out_size, void* d_ws, size_t ws_size,
                              hipStream_t stream)
{
    const float* Q  = (const float*)d_in[0];
    const float* V  = (const float*)d_in[1];
    const float* K  = (const float*)d_in[2];
    const float* Wq = (const float*)d_in[3];
    const float* bq = (const float*)d_in[4];
    const float* bk = (const float*)d_in[6];
    const float* Wk = (const float*)d_in[5];
    const float* Wv = (const float*)d_in[7];
    const float* bv = (const float*)d_in[8];
    unsigned short* ws = (unsigned short*)d_ws;   // 6 planes * 2MB = 12MB
    float* out = (float*)d_out;

    dim3 gp(S_LEN/64, C_DIM/64, 3);
    proj_mfma<<<gp, 256, 0, stream>>>(Q, V, K, Wq, bq, Wk, bk, Wv, bv, ws);

    attn_mfma<<<dim3(128*NH), 512, 0, stream>>>(ws, out);
}

// Round 6
// 139.445 us; speedup vs baseline: 1.7581x; 1.0198x over previous
//
#include <hip/hip_runtime.h>
#include <math.h>

#define S_LEN 2048
#define C_DIM 512
#define NH 16
#define HD 32
#define PLANE_U (NH * S_LEN * HD)   // 1,048,576 ushorts = 2MB per plane

typedef __attribute__((ext_vector_type(8))) short bf16x8;
typedef __attribute__((ext_vector_type(8))) unsigned short u16x8;
typedef __attribute__((ext_vector_type(4))) float f32x4;

__device__ __forceinline__ unsigned short f2b(float f) {
    unsigned int x = __float_as_uint(f);
    unsigned int r = (x + 0x7FFFu + ((x >> 16) & 1u)) >> 16;   // RNE
    return (unsigned short)r;
}
__device__ __forceinline__ unsigned int pk2(float a, float b) {
    return (unsigned int)f2b(a) | ((unsigned int)f2b(b) << 16);
}

// split x into bf16 hi (truncated) + bf16 lo (RNE of residual): hi+lo ~ 2^-17 rel
__device__ __forceinline__ void cvt_hilo(float x, unsigned short& hi, unsigned short& lo) {
    unsigned int b = __float_as_uint(x);
    hi = (unsigned short)(b >> 16);
    float hif = __uint_as_float(b & 0xFFFF0000u);
    lo = f2b(x - hif);
}

// ---------------- projection: complex GEMM via bf16 MFMA, hi/lo split ------
// z<2 (q,k): D = W·X^T (rows=o, cols=s) -> store ushort4 along d in [h][s][d]
// z==2 (v):  D = X·W^T (rows=s, cols=o) -> store ushort4 along s in [h][d][s]
#define PROW 40   // padded LDS row stride in ushorts (80B, 16B-aligned)

__global__ __launch_bounds__(256)
void proj_mfma(const float* __restrict__ Q, const float* __restrict__ V,
               const float* __restrict__ K,
               const float* __restrict__ Wq, const float* __restrict__ bq,
               const float* __restrict__ Wk, const float* __restrict__ bk,
               const float* __restrict__ Wv, const float* __restrict__ bv,
               unsigned short* __restrict__ ws)
{
    const int z = blockIdx.z;
    const float *X, *W, *b;
    if (z == 0)      { X = Q; W = Wq; b = bq; }
    else if (z == 1) { X = K; W = Wk; b = bk; }
    else             { X = V; W = Wv; b = bv; }

    const int s0 = blockIdx.x * 64;
    const int o0 = blockIdx.y * 64;

    const float2 *Asrc, *Bsrc; int arow0, brow0;
    if (z < 2) { Asrc = (const float2*)W; arow0 = o0; Bsrc = (const float2*)X; brow0 = s0; }
    else       { Asrc = (const float2*)X; arow0 = s0; Bsrc = (const float2*)W; brow0 = o0; }

    __shared__ __align__(16) unsigned short LArh[64*PROW], LArl[64*PROW];
    __shared__ __align__(16) unsigned short LAih[64*PROW], LAil[64*PROW];
    __shared__ __align__(16) unsigned short LBrh[64*PROW], LBrl[64*PROW];
    __shared__ __align__(16) unsigned short LBih[64*PROW], LBil[64*PROW];

    const int t    = threadIdx.x;
    const int wave = t >> 6;
    const int lr   = t & 15;
    const int g    = (t & 63) >> 4;
    const int srow = t >> 2;        // staging row 0..63
    const int sk8  = (t & 3) * 8;   // staging k chunk (8 complex)

    const f32x4 zf = {0.f,0.f,0.f,0.f};
    f32x4 accR[4], accI[4];
    #pragma unroll
    for (int i = 0; i < 4; ++i) { accR[i] = zf; accI[i] = zf; }

    for (int k0 = 0; k0 < C_DIM; k0 += 32) {
        __syncthreads();
        // ---- stage A tile ----
        {
            const float4* s4 = (const float4*)(Asrc + (size_t)(arow0 + srow)*C_DIM + k0 + sk8);
            float4 f0 = s4[0], f1 = s4[1], f2v = s4[2], f3 = s4[3];
            float re[8] = {f0.x,f0.z,f1.x,f1.z,f2v.x,f2v.z,f3.x,f3.z};
            float im[8] = {f0.y,f0.w,f1.y,f1.w,f2v.y,f2v.w,f3.y,f3.w};
            u16x8 rh, rl, ih, il;
            #pragma unroll
            for (int j = 0; j < 8; ++j) {
                unsigned short h_, l_;
                cvt_hilo(re[j], h_, l_); rh[j] = h_; rl[j] = l_;
                cvt_hilo(im[j], h_, l_); ih[j] = h_; il[j] = l_;
            }
            int wb = srow*PROW + sk8;
            *(u16x8*)&LArh[wb] = rh; *(u16x8*)&LArl[wb] = rl;
            *(u16x8*)&LAih[wb] = ih; *(u16x8*)&LAil[wb] = il;
        }
        // ---- stage B tile ----
        {
            const float4* s4 = (const float4*)(Bsrc + (size_t)(brow0 + srow)*C_DIM + k0 + sk8);
            float4 f0 = s4[0], f1 = s4[1], f2v = s4[2], f3 = s4[3];
            float re[8] = {f0.x,f0.z,f1.x,f1.z,f2v.x,f2v.z,f3.x,f3.z};
            float im[8] = {f0.y,f0.w,f1.y,f1.w,f2v.y,f2v.w,f3.y,f3.w};
            u16x8 rh, rl, ih, il;
            #pragma unroll
            for (int j = 0; j < 8; ++j) {
                unsigned short h_, l_;
                cvt_hilo(re[j], h_, l_); rh[j] = h_; rl[j] = l_;
                cvt_hilo(im[j], h_, l_); ih[j] = h_; il[j] = l_;
            }
            int wb = srow*PROW + sk8;
            *(u16x8*)&LBrh[wb] = rh; *(u16x8*)&LBrl[wb] = rl;
            *(u16x8*)&LBih[wb] = ih; *(u16x8*)&LBil[wb] = il;
        }
        __syncthreads();

        // ---- A fragments (wave's 16 rows) ----
        const int ab = (wave*16 + lr)*PROW + g*8;
        bf16x8 aRH = *(const bf16x8*)&LArh[ab];
        bf16x8 aRL = *(const bf16x8*)&LArl[ab];
        bf16x8 aIH = *(const bf16x8*)&LAih[ab];
        bf16x8 aIL = *(const bf16x8*)&LAil[ab];
        bf16x8 aIHn, aILn;
        #pragma unroll
        for (int j = 0; j < 8; ++j) { aIHn[j] = aIH[j] ^ (short)0x8000; aILn[j] = aIL[j] ^ (short)0x8000; }

        #pragma unroll
        for (int tile = 0; tile < 4; ++tile) {
            const int bb = (tile*16 + lr)*PROW + g*8;
            bf16x8 bRH = *(const bf16x8*)&LBrh[bb];
            bf16x8 bRL = *(const bf16x8*)&LBrl[bb];
            bf16x8 bIH = *(const bf16x8*)&LBih[bb];
            bf16x8 bIL = *(const bf16x8*)&LBil[bb];
            // Re: aR*bR - aI*bI (hi*hi + hi*lo + lo*hi)
            accR[tile] = __builtin_amdgcn_mfma_f32_16x16x32_bf16(aRH,  bRH, accR[tile], 0,0,0);
            accR[tile] = __builtin_amdgcn_mfma_f32_16x16x32_bf16(aRL,  bRH, accR[tile], 0,0,0);
            accR[tile] = __builtin_amdgcn_mfma_f32_16x16x32_bf16(aRH,  bRL, accR[tile], 0,0,0);
            accR[tile] = __builtin_amdgcn_mfma_f32_16x16x32_bf16(aIHn, bIH, accR[tile], 0,0,0);
            accR[tile] = __builtin_amdgcn_mfma_f32_16x16x32_bf16(aILn, bIH, accR[tile], 0,0,0);
            accR[tile] = __builtin_amdgcn_mfma_f32_16x16x32_bf16(aIHn, bIL, accR[tile], 0,0,0);
            // Im: aR*bI + aI*bR
            accI[tile] = __builtin_amdgcn_mfma_f32_16x16x32_bf16(aRH,  bIH, accI[tile], 0,0,0);
            accI[tile] = __builtin_amdgcn_mfma_f32_16x16x32_bf16(aRL,  bIH, accI[tile], 0,0,0);
            accI[tile] = __builtin_amdgcn_mfma_f32_16x16x32_bf16(aRH,  bIL, accI[tile], 0,0,0);
            accI[tile] = __builtin_amdgcn_mfma_f32_16x16x32_bf16(aIH,  bRH, accI[tile], 0,0,0);
            accI[tile] = __builtin_amdgcn_mfma_f32_16x16x32_bf16(aIL,  bRH, accI[tile], 0,0,0);
            accI[tile] = __builtin_amdgcn_mfma_f32_16x16x32_bf16(aIH,  bRL, accI[tile], 0,0,0);
        }
    }

    // ---- epilogue ----
    const float2* b2 = (const float2*)b;
    if (z < 2) {
        unsigned short* pr = ws + (z == 0 ? 0 : 2) * (size_t)PLANE_U;
        unsigned short* pi = pr + PLANE_U;
        const int obase = o0 + wave*16 + g*4;
        const int h = obase >> 5, d0 = obase & 31;
        float bR[4], bI[4];
        #pragma unroll
        for (int r = 0; r < 4; ++r) { float2 bb = b2[obase + r]; bR[r] = bb.x; bI[r] = bb.y; }
        #pragma unroll
        for (int tile = 0; tile < 4; ++tile) {
            int s = s0 + tile*16 + lr;
            size_t idx = ((size_t)h*S_LEN + s)*HD + d0;
            ushort4 pkR, pkI;
            pkR.x = f2b(accR[tile][0]+bR[0]); pkR.y = f2b(accR[tile][1]+bR[1]);
            pkR.z = f2b(accR[tile][2]+bR[2]); pkR.w = f2b(accR[tile][3]+bR[3]);
            pkI.x = f2b(accI[tile][0]+bI[0]); pkI.y = f2b(accI[tile][1]+bI[1]);
            pkI.z = f2b(accI[tile][2]+bI[2]); pkI.w = f2b(accI[tile][3]+bI[3]);
            *(ushort4*)&pr[idx] = pkR;
            *(ushort4*)&pi[idx] = pkI;
        }
    } else {
        unsigned short* tr = ws + 4 * (size_t)PLANE_U;
        unsigned short* ti = tr + PLANE_U;
        const int sbase = s0 + wave*16 + g*4;
        #pragma unroll
        for (int tile = 0; tile < 4; ++tile) {
            int o = o0 + tile*16 + lr;
            int h = o >> 5, d = o & 31;
            float2 bb = b2[o];
            size_t idx = ((size_t)h*HD + d)*S_LEN + sbase;
            ushort4 pkR, pkI;
            pkR.x = f2b(accR[tile][0]+bb.x); pkR.y = f2b(accR[tile][1]+bb.x);
            pkR.z = f2b(accR[tile][2]+bb.x); pkR.w = f2b(accR[tile][3]+bb.x);
            pkI.x = f2b(accI[tile][0]+bb.y); pkI.y = f2b(accI[tile][1]+bb.y);
            pkI.z = f2b(accI[tile][2]+bb.y); pkI.w = f2b(accI[tile][3]+bb.y);
            *(ushort4*)&tr[idx] = pkR;
            *(ushort4*)&ti[idx] = pkI;
        }
    }
}

// ---------------- MFMA flash attention, block-cooperative split-K --------
// SWAPPED QK^T: S-tile = mfma(K, Q) so D[key][q] has col=q=lane&15 -> each
// lane holds 4 consecutive keys of ONE q-row per tile: P-write is a single
// ds_write_b64 per tile-subloop (4/tile vs 16 scalar b16), l-sum is lane-
// local (2 shfl at end). Partials purely additive (no max tracking; |s|<=~15).
// launch_bounds min-waves stays 4: 8 caps at 32 VGPR and spills (round 4).
#define RED_F2 (8*16*32)          // 4096 float2 = 32KB partial-O region

__global__ __launch_bounds__(512, 4)
void attn_mfma(const unsigned short* __restrict__ ws, float* __restrict__ out)
{
    const int bid   = blockIdx.x;
    const int h     = bid & (NH - 1);   // bid%8 = head%8 -> per-XCD KV locality
    const int strip = bid >> 4;         // 0..127
    const int wave  = threadIdx.x >> 6; // 0..7 -> k-range owner
    const int lr    = threadIdx.x & 15;
    const int g     = (threadIdx.x & 63) >> 4;

    const unsigned short* qr  = ws + 0*(size_t)PLANE_U + (size_t)h*S_LEN*HD;
    const unsigned short* qi  = ws + 1*(size_t)PLANE_U + (size_t)h*S_LEN*HD;
    const unsigned short* kr  = ws + 2*(size_t)PLANE_U + (size_t)h*S_LEN*HD;
    const unsigned short* ki  = ws + 3*(size_t)PLANE_U + (size_t)h*S_LEN*HD;
    const unsigned short* vtr = ws + 4*(size_t)PLANE_U + (size_t)h*HD*S_LEN;
    const unsigned short* vti = ws + 5*(size_t)PLANE_U + (size_t)h*HD*S_LEN;

    const int q0 = strip * 16;

    // Q fragments (B-operand): lane supplies Q[q=lr][k=g*8+j]
    bf16x8 bQr = *(const bf16x8*)&qr[(size_t)(q0 + lr)*HD + g*8];
    bf16x8 bQi = *(const bf16x8*)&qi[(size_t)(q0 + lr)*HD + g*8];
    bf16x8 bQrn;
    #pragma unroll
    for (int j = 0; j < 8; ++j) bQrn[j] = bQr[j] ^ (short)0x8000;

    // phase 1: per-wave 2KB P buffers (16KB); phase 2 (after barrier): the
    // same space is reused as the 32KB+512B partial-reduce region.
    __shared__ __align__(16) char smem[RED_F2*8 + 8*16*4];
    char* pb = smem + wave*2048;

    const f32x4 zf = {0.f, 0.f, 0.f, 0.f};
    f32x4 accO[2][2];
    #pragma unroll
    for (int dt = 0; dt < 2; ++dt) { accO[dt][0] = zf; accO[dt][1] = zf; }
    float l_lane = 0.f;   // partial denom for q=lr (this lane's row slice)

    const int kbeg = wave * 256;
    const float sc2 = 1.0f / 32.0f;
    for (int k0 = kbeg; k0 < kbeg + 256; k0 += 64) {
        // ---- per 16-key subtile: 4 mfma -> softmax -> one b64 P-write ----
        #pragma unroll
        for (int t = 0; t < 4; ++t) {
            const size_t krow = (size_t)(k0 + t*16 + lr)*HD + g*8;
            bf16x8 aKr = *(const bf16x8*)&kr[krow];
            bf16x8 aKi = *(const bf16x8*)&ki[krow];
            // D[key][q]: re = kr.qr + ki.qi ; im = kr.qi + ki.(-qr)
            f32x4 sR = __builtin_amdgcn_mfma_f32_16x16x32_bf16(aKi, bQi,  zf, 0, 0, 0);
            sR       = __builtin_amdgcn_mfma_f32_16x16x32_bf16(aKr, bQr,  sR, 0, 0, 0);
            f32x4 sI = __builtin_amdgcn_mfma_f32_16x16x32_bf16(aKi, bQrn, zf, 0, 0, 0);
            sI       = __builtin_amdgcn_mfma_f32_16x16x32_bf16(aKr, bQi,  sI, 0, 0, 0);
            // lane holds S[key = t*16 + g*4 + r][q = lr], r=0..3
            float p[4];
            #pragma unroll
            for (int r = 0; r < 4; ++r) {
                p[r] = __expf(__builtin_amdgcn_sqrtf(
                    fmaf(sR[r], sR[r], sI[r]*sI[r]) * sc2));
                l_lane += p[r];
            }
            // P[q=lr][keys t*16+g*4 .. +3] -> one 8B swizzled write
            uint2 pk; pk.x = pk2(p[0], p[1]); pk.y = pk2(p[2], p[3]);
            int boff = (lr*128 + (t*16 + g*4)*2) ^ ((lr & 7) << 4);
            *(uint2*)(pb + boff) = pk;
        }
        // ---- PV: A = P from LDS, B = V^T planes (contiguous) ----
        #pragma unroll
        for (int ks = 0; ks < 2; ++ks) {
            int rboff = (lr*128 + ks*64 + g*16) ^ ((lr & 7) << 4);
            bf16x8 aP = *(const bf16x8*)(pb + rboff);
            const size_t vcol = (size_t)k0 + ks*32 + g*8;
            #pragma unroll
            for (int dt = 0; dt < 2; ++dt) {
                bf16x8 bVr = *(const bf16x8*)&vtr[(size_t)(dt*16 + lr)*S_LEN + vcol];
                bf16x8 bVi = *(const bf16x8*)&vti[(size_t)(dt*16 + lr)*S_LEN + vcol];
                accO[dt][0] = __builtin_amdgcn_mfma_f32_16x16x32_bf16(aP, bVr, accO[dt][0], 0, 0, 0);
                accO[dt][1] = __builtin_amdgcn_mfma_f32_16x16x32_bf16(aP, bVi, accO[dt][1], 0, 0, 0);
            }
        }
    }

    // ---- wave l-reduction: q=lr slices live at lanes lr, lr+16, lr+32, lr+48
    l_lane += __shfl_xor(l_lane, 16);
    l_lane += __shfl_xor(l_lane, 32);

    // ---- block combine: all P buffers dead; alias smem as reduce region ----
    __syncthreads();
    float2* red  = (float2*)smem;                 // [8][16][32] complex partials
    float*  lred = (float*)(smem + RED_F2*8);     // [8][16]
    #pragma unroll
    for (int r = 0; r < 4; ++r) {
        int q = g*4 + r;
        #pragma unroll
        for (int dt = 0; dt < 2; ++dt) {
            int d = dt*16 + lr;
            red[wave*512 + q*32 + d] = make_float2(accO[dt][0][r], accO[dt][1][r]);
        }
    }
    if (g == 0) lred[wave*16 + lr] = l_lane;      // l for q=lr
    __syncthreads();

    // thread i sums partials for output element (q = i>>5, d = i&31)
    {
        const int i = threadIdx.x;
        const int q = i >> 5, d = i & 31;
        float sr = 0.f, si = 0.f, sl = 0.f;
        #pragma unroll
        for (int w = 0; w < 8; ++w) {
            float2 v = red[w*512 + q*32 + d];
            sr += v.x; si += v.y;
            sl += lred[w*16 + q];
        }
        float inv = 1.0f / sl;
        float2* o2 = (float2*)out;
        o2[(size_t)(q0 + q)*C_DIM + h*HD + d] = make_float2(sr*inv, si*inv);
    }
}

extern "C" void kernel_launch(void* const* d_in, const int* in_sizes, int n_in,
                              void* d_out, int out_size, void* d_ws, size_t ws_size,
                              hipStream_t stream)
{
    const float* Q  = (const float*)d_in[0];
    const float* V  = (const float*)d_in[1];
    const float* K  = (const float*)d_in[2];
    const float* Wq = (const float*)d_in[3];
    const float* bq = (const float*)d_in[4];
    const float* Wk = (const float*)d_in[5];
    const float* bk = (const float*)d_in[6];
    const float* Wv = (const float*)d_in[7];
    const float* bv = (const float*)d_in[8];
    unsigned short* ws = (unsigned short*)d_ws;   // 6 planes * 2MB = 12MB
    float* out = (float*)d_out;

    dim3 gp(S_LEN/64, C_DIM/64, 3);
    proj_mfma<<<gp, 256, 0, stream>>>(Q, V, K, Wq, bq, Wk, bk, Wv, bv, ws);

    attn_mfma<<<dim3(128*NH), 512, 0, stream>>>(ws, out);
}